// Round 2
// baseline (375.995 us; speedup 1.0000x reference)
//
#include <hip/hip_runtime.h>

#define BB 256
#define CC 68
#define HH 64
#define WW 64
#define NCH (BB * CC)          // 17408 channels
#define NBLK 544               // 544 blocks * 4 waves = 2176 waves; 17408/2176 = 8 channels/wave

__global__ __launch_bounds__(256) void face_landmark_kernel(
    const float* __restrict__ pred_hm,   // [B,C,H,W]
    const float* __restrict__ center,    // [B,2]
    const float* __restrict__ scale,     // [B]
    float* __restrict__ out)             // [B,C,2]
{
    const int lane = threadIdx.x & 63;
    const int wave = blockIdx.x * 4 + (threadIdx.x >> 6);
    const int nwaves = NBLK * 4;

    for (int ch = wave; ch < NCH; ch += nwaves) {
        const float* hm = pred_hm + (size_t)ch * (HH * WW);
        const float4* hm4 = (const float4*)hm;

        // 16 independent float4 loads per lane — deep memory-level parallelism,
        // no cross-wave dependency, no barrier.
        float4 v[16];
#pragma unroll
        for (int k = 0; k < 16; ++k) v[k] = hm4[lane + 64 * k];

        // Per-lane argmax; indices ascend with k, strict > keeps first occurrence.
        float best_v = -__builtin_inff();
        int   best_i = 0;
#pragma unroll
        for (int k = 0; k < 16; ++k) {
            const int base = (lane + 64 * k) * 4;
            if (v[k].x > best_v) { best_v = v[k].x; best_i = base;     }
            if (v[k].y > best_v) { best_v = v[k].y; best_i = base + 1; }
            if (v[k].z > best_v) { best_v = v[k].z; best_i = base + 2; }
            if (v[k].w > best_v) { best_v = v[k].w; best_i = base + 3; }
        }

        // Wave-64 reduce; tie -> smaller index (first occurrence).
#pragma unroll
        for (int off = 32; off > 0; off >>= 1) {
            const float ov = __shfl_down(best_v, off, 64);
            const int   oi = __shfl_down(best_i, off, 64);
            if (ov > best_v || (ov == best_v && oi < best_i)) { best_v = ov; best_i = oi; }
        }

        if (lane == 0) {
            const int idx = best_i;          // 0-based flat argmax
            const int iX = idx & (WW - 1);   // column
            const int iY = idx >> 6;         // row
            float px = (float)(iX + 1);      // 1-based
            float py = (float)(iY + 1);

            const bool interior = (iX > 0) && (iX < WW - 1) && (iY > 0) && (iY < HH - 1);
            if (interior) {
                const float dx = hm[iY * WW + iX + 1] - hm[iY * WW + iX - 1];
                const float dy = hm[(iY + 1) * WW + iX] - hm[(iY - 1) * WW + iX];
                px += (dx > 0.0f) ? 0.25f : ((dx < 0.0f) ? -0.25f : 0.0f);
                py += (dy > 0.0f) ? 0.25f : ((dy < 0.0f) ? -0.25f : 0.0f);
            }
            px -= 0.5f;
            py -= 0.5f;

            const int b = ch / CC;
            const float h  = 200.0f * scale[b];
            const float hr = h * (1.0f / (float)HH);     // h / res, res = H = 64
            const float ox = px * hr + center[b * 2 + 0] - 0.5f * h;
            const float oy = py * hr + center[b * 2 + 1] - 0.5f * h;

            ((float2*)out)[ch] = make_float2(ox, oy);
        }
    }
}

extern "C" void kernel_launch(void* const* d_in, const int* in_sizes, int n_in,
                              void* d_out, int out_size, void* d_ws, size_t ws_size,
                              hipStream_t stream) {
    const float* pred_hm = (const float*)d_in[0];   // [256,68,64,64] f32
    const float* center  = (const float*)d_in[1];   // [256,2] f32
    const float* scale   = (const float*)d_in[2];   // [256] f32
    float* out = (float*)d_out;                     // [256,68,2] f32

    face_landmark_kernel<<<dim3(NBLK), dim3(256), 0, stream>>>(
        pred_hm, center, scale, out);
}